// Round 7
// baseline (160.765 us; speedup 1.0000x reference)
//
#include <hip/hip_runtime.h>
#include <hip/hip_bf16.h>

#define BB 32
#define SS 4096
#define DD 128
#define HH 8

typedef __attribute__((ext_vector_type(8))) short short8;   // 8 bf16 (MFMA A/B frag)
typedef __attribute__((ext_vector_type(4))) float f32x4;    // MFMA C/D frag
typedef unsigned long long u64;

// fp32 -> bf16 round-to-nearest-even (bit pattern)
__device__ inline unsigned short f2b(float f){
  unsigned int u = __float_as_uint(f);
  return (unsigned short)((u + 0x7fffu + ((u >> 16) & 1u)) >> 16);
}

// Swizzled element index in a [R][128] bf16 LDS tile (16B blocks XOR row&7).
__device__ inline int swzi(int r, int c){
  return (r << 7) | (((c >> 3) ^ (r & 7)) << 3) | (c & 7);
}

// MFMA A/B fragment read from swizzled LDS tile.
__device__ inline short8 ldfrag(const short* buf, int row, int kblk){
  return *reinterpret_cast<const short8*>(&buf[(row << 7) | ((kblk ^ (row & 7)) << 3)]);
}

// MFMA A fragment DIRECT from row-major fp32 global (no LDS): lane -> row,
// 8 consecutive d at kblk*8.
__device__ inline short8 ldxfrag(const float* __restrict__ base, int row, int kblk){
  const float4* p = reinterpret_cast<const float4*>(base) + row * 32 + kblk * 2;
  float4 a = p[0], b = p[1];
  short8 r;
  r[0] = (short)f2b(a.x); r[1] = (short)f2b(a.y); r[2] = (short)f2b(a.z); r[3] = (short)f2b(a.w);
  r[4] = (short)f2b(b.x); r[5] = (short)f2b(b.y); r[6] = (short)f2b(b.z); r[7] = (short)f2b(b.w);
  return r;
}

// 32x64 wave tile: C[wm..+31][wn..+63] += A(rows of bufA) * B^T(rows of bufB), K=128
__device__ inline void wave_gemm32x64(const short* bufA, const short* bufB,
                                      int wm, int wn, int lane, f32x4 acc[2][4]){
  #pragma unroll
  for (int ks = 0; ks < 4; ++ks){
    int kblk = ks * 4 + (lane >> 4);
    short8 af[2], bf[4];
    #pragma unroll
    for (int mt = 0; mt < 2; ++mt) af[mt] = ldfrag(bufA, wm + mt * 16 + (lane & 15), kblk);
    #pragma unroll
    for (int nt = 0; nt < 4; ++nt) bf[nt] = ldfrag(bufB, wn + nt * 16 + (lane & 15), kblk);
    #pragma unroll
    for (int mt = 0; mt < 2; ++mt)
      #pragma unroll
      for (int nt = 0; nt < 4; ++nt)
        acc[mt][nt] = __builtin_amdgcn_mfma_f32_16x16x32_bf16(af[mt], bf[nt], acc[mt][nt], 0, 0, 0);
  }
}

// 32x32 wave tile (for k_heads split-g): acc[2][2]
__device__ inline void wave_gemm32x32(const short* bufA, const short* bufB,
                                      int wm, int wn, int lane, f32x4 acc[2][2]){
  #pragma unroll
  for (int ks = 0; ks < 4; ++ks){
    int kblk = ks * 4 + (lane >> 4);
    short8 af[2], bf[2];
    #pragma unroll
    for (int mt = 0; mt < 2; ++mt) af[mt] = ldfrag(bufA, wm + mt * 16 + (lane & 15), kblk);
    #pragma unroll
    for (int nt = 0; nt < 2; ++nt) bf[nt] = ldfrag(bufB, wn + nt * 16 + (lane & 15), kblk);
    #pragma unroll
    for (int mt = 0; mt < 2; ++mt)
      #pragma unroll
      for (int nt = 0; nt < 2; ++nt)
        acc[mt][nt] = __builtin_amdgcn_mfma_f32_16x16x32_bf16(af[mt], bf[nt], acc[mt][nt], 0, 0, 0);
  }
}

__device__ inline u64 packb4(float a, float b, float c, float d){
  return (u64)f2b(a) | ((u64)f2b(b) << 16) | ((u64)f2b(c) << 32) | ((u64)f2b(d) << 48);
}

// fp32 [R][128] row-major -> swizzled bf16 LDS, 512 threads.
template<int R>
__device__ inline void stageR(const float* __restrict__ src, short* dst, int t){
  const float4* s4 = reinterpret_cast<const float4*>(src);
  #pragma unroll
  for (int f4 = t; f4 < R * 32; f4 += 512){
    int r = f4 >> 5, c = (f4 & 31) << 2;
    float4 v = s4[f4];
    *reinterpret_cast<u64*>(&dst[swzi(r, c)]) = packb4(v.x, v.y, v.z, v.w);
  }
}

// reg-staged variant (issue-early / write-late), 512 threads: 8 float4 per thread
__device__ inline void ld128(const float* __restrict__ src, int t, float4 r[8]){
  const float4* s4 = reinterpret_cast<const float4*>(src);
  #pragma unroll
  for (int i = 0; i < 8; ++i) r[i] = s4[t + i * 512];
}
__device__ inline void wr128(short* dst, int t, const float4 r[8]){
  #pragma unroll
  for (int i = 0; i < 8; ++i){
    int f4 = t + i * 512;
    int rr = f4 >> 5, c = (f4 & 31) << 2;
    *reinterpret_cast<u64*>(&dst[swzi(rr, c)]) = packb4(r[i].x, r[i].y, r[i].z, r[i].w);
  }
}

// ---------------- Kernel 1: Gf[b] += slot-partial of x[b]^T x[b] (device atomicAdd) ----------------
// grid (8, B), 512 threads. Accumulation via device-scope fp32 atomics (proven round 0).
__global__ __launch_bounds__(512) void k_gram(const float* __restrict__ x, float* __restrict__ Gf){
  __shared__ short xsT[128 * 128];   // 32 KB, x^T chunk swizzled
  const int t = threadIdx.x, lane = t & 63, wid = t >> 6;
  const int slot = blockIdx.x, b = blockIdx.y;
  const int e = t & 127, sb0 = t >> 7;            // sb0 in [0,4): base s-block (8 s each)
  const int wm = (wid >> 1) * 32, wn = (wid & 1) * 64;

  f32x4 acc[2][4];
  const f32x4 z = {0.f, 0.f, 0.f, 0.f};
  #pragma unroll
  for (int i = 0; i < 2; ++i)
    #pragma unroll
    for (int j = 0; j < 4; ++j) acc[i][j] = z;

  const float* xb = x + ((size_t)b * SS + slot * 512) * DD;
  float v[4][8];
  #pragma unroll
  for (int i = 0; i < 4; ++i)
    #pragma unroll
    for (int j = 0; j < 8; ++j)
      v[i][j] = xb[(size_t)(((sb0 + 4 * i) * 8 + j)) * DD + e];

  for (int c = 0; c < 4; ++c){
    __syncthreads();                 // previous gemm's reads of xsT done
    #pragma unroll
    for (int i = 0; i < 4; ++i){     // b128 transposed writes, conflict-free
      int sb = sb0 + 4 * i;
      short8 w;
      #pragma unroll
      for (int j = 0; j < 8; ++j) w[j] = (short)f2b(v[i][j]);
      *reinterpret_cast<short8*>(&xsT[(e << 7) | ((sb ^ (e & 7)) << 3)]) = w;
    }
    if (c < 3){                      // issue next chunk: in flight across gemm below
      const float* src = xb + (size_t)(c + 1) * 128 * DD;
      #pragma unroll
      for (int i = 0; i < 4; ++i)
        #pragma unroll
        for (int j = 0; j < 8; ++j)
          v[i][j] = src[(size_t)(((sb0 + 4 * i) * 8 + j)) * DD + e];
    }
    __syncthreads();
    wave_gemm32x64(xsT, xsT, wm, wn, lane, acc);
  }

  float* Gb = Gf + (size_t)b * (DD * DD);
  #pragma unroll
  for (int mt = 0; mt < 2; ++mt)
    #pragma unroll
    for (int nt = 0; nt < 4; ++nt)
      #pragma unroll
      for (int i = 0; i < 4; ++i){
        int ee = wm + mt * 16 + ((lane >> 4) << 2) + i;
        int ff = wn + nt * 16 + (lane & 15);
        atomicAdd(&Gb[(ee << 7) + ff], acc[mt][nt][i]);
      }
}

// ---------------- Kernel 2: Mf[b] += (Wkq[h] G[b] Wv[h]^T)^T half-tile (device atomicAdd) ----------------
// grid (2H, B): bx = h*2+gh. Stages fp32 G[b] itself (kernel-boundary visibility).
__global__ __launch_bounds__(512) void k_heads(const float* __restrict__ Gf,
                                               const float* __restrict__ Wkq,
                                               const float* __restrict__ Wv,
                                               float* __restrict__ Mf){
  __shared__ short bufA[64 * 128];    // 16 KB: Wv-half, then Tt-half
  __shared__ short bufB[128 * 128];   // 32 KB: G, then Wkq
  const int t = threadIdx.x, lane = t & 63, wid = t >> 6;
  const int h = blockIdx.x >> 1, gh = blockIdx.x & 1, b = blockIdx.y;
  const int wm = (wid >> 2) * 32, wn = (wid & 3) * 32;
  const f32x4 z = {0.f, 0.f, 0.f, 0.f};

  stageR<64>(Wv + (size_t)h * DD * DD + (size_t)gh * 64 * DD, bufA, t);
  stageR<128>(Gf + (size_t)b * DD * DD, bufB, t);   // fp32 G -> bf16 swizzled (L2-hot)
  __syncthreads();

  float4 wk[8];
  ld128(Wkq + (size_t)h * DD * DD, t, wk);   // early issue, lands during gemm1

  f32x4 acc[2][2];
  #pragma unroll
  for (int i = 0; i < 2; ++i)
    #pragma unroll
    for (int j = 0; j < 2; ++j) acc[i][j] = z;
  // Tt[g'][e] = sum_f Wv[gh*64+g'][f] * G[e][f]   (G symmetric)
  wave_gemm32x32(bufA, bufB, wm, wn, lane, acc);
  __syncthreads();                            // all gemm1 reads done before overwrite

  #pragma unroll
  for (int mt = 0; mt < 2; ++mt)
    #pragma unroll
    for (int nt = 0; nt < 2; ++nt)
      #pragma unroll
      for (int i = 0; i < 4; ++i){
        int g = wm + mt * 16 + ((lane >> 4) << 2) + i;
        int e = wn + nt * 16 + (lane & 15);
        bufA[swzi(g, e)] = (short)f2b(acc[mt][nt][i]);
      }
  wr128(bufB, t, wk);                         // Wkq into bufB
  __syncthreads();

  #pragma unroll
  for (int i = 0; i < 2; ++i)
    #pragma unroll
    for (int j = 0; j < 2; ++j) acc[i][j] = z;
  // Mt[g'][d] = sum_e Tt[g'][e] * Wkq[d][e]  (swap -> transposed result)
  wave_gemm32x32(bufA, bufB, wm, wn, lane, acc);

  float* Mb = Mf + (size_t)b * (DD * DD) + (size_t)gh * 64 * DD;
  #pragma unroll
  for (int mt = 0; mt < 2; ++mt)
    #pragma unroll
    for (int nt = 0; nt < 2; ++nt)
      #pragma unroll
      for (int i = 0; i < 4; ++i){
        int g = wm + mt * 16 + ((lane >> 4) << 2) + i;
        int d = wn + nt * 16 + (lane & 15);
        atomicAdd(&Mb[(g << 7) + d], acc[mt][nt][i]);
      }
}

// ---------------- Kernel 3: out[b][s][g] = sum_d x[b][s][d] * Mt[b][g][d] ----------------
// Stages fp32 M[b] itself; A-fragments DIRECT from global fp32 x. One barrier.
__global__ __launch_bounds__(512) void k_out(const float* __restrict__ x,
                                             const float* __restrict__ Mf,
                                             float* __restrict__ out){
  __shared__ short bufM[128 * 128];
  const int t = threadIdx.x, lane = t & 63, wid = t >> 6;
  const int b = blockIdx.y, s0 = blockIdx.x * 256;
  const int wm = (wid >> 1) * 32, wn = (wid & 1) * 64;
  const f32x4 z = {0.f, 0.f, 0.f, 0.f};

  stageR<128>(Mf + (size_t)b * DD * DD, bufM, t);   // fp32 M^T -> bf16 swizzled (L2-hot)
  __syncthreads();

  const float* xb = x + ((size_t)b * SS + s0) * DD;
  #pragma unroll
  for (int c = 0; c < 2; ++c){
    f32x4 acc[2][4];
    #pragma unroll
    for (int i = 0; i < 2; ++i)
      #pragma unroll
      for (int j = 0; j < 4; ++j) acc[i][j] = z;

    #pragma unroll
    for (int ks = 0; ks < 4; ++ks){
      int kblk = ks * 4 + (lane >> 4);
      short8 af[2], bf[4];
      #pragma unroll
      for (int mt = 0; mt < 2; ++mt)
        af[mt] = ldxfrag(xb, c * 128 + wm + mt * 16 + (lane & 15), kblk);
      #pragma unroll
      for (int nt = 0; nt < 4; ++nt) bf[nt] = ldfrag(bufM, wn + nt * 16 + (lane & 15), kblk);
      #pragma unroll
      for (int mt = 0; mt < 2; ++mt)
        #pragma unroll
        for (int nt = 0; nt < 4; ++nt)
          acc[mt][nt] = __builtin_amdgcn_mfma_f32_16x16x32_bf16(af[mt], bf[nt], acc[mt][nt], 0, 0, 0);
    }

    float* ob = out + ((size_t)b * SS + s0 + c * 128) * DD;
    #pragma unroll
    for (int mt = 0; mt < 2; ++mt)
      #pragma unroll
      for (int nt = 0; nt < 4; ++nt)
        #pragma unroll
        for (int i = 0; i < 4; ++i){
          int sp = wm + mt * 16 + ((lane >> 4) << 2) + i;
          int g = wn + nt * 16 + (lane & 15);
          ob[(sp << 7) + g] = acc[mt][nt][i];
        }
  }
}

extern "C" void kernel_launch(void* const* d_in, const int* in_sizes, int n_in,
                              void* d_out, int out_size, void* d_ws, size_t ws_size,
                              hipStream_t stream) {
  const float* x   = (const float*)d_in[0];
  const float* Wkq = (const float*)d_in[1];
  const float* Wv  = (const float*)d_in[2];
  float* out = (float*)d_out;

  float* Gf = (float*)d_ws;                 // [B][128][128] fp32 = 2 MB (atomic accum)
  float* Mf = Gf + (size_t)BB * DD * DD;    // [B][128][128] fp32 = 2 MB (atomic accum, M^T)

  hipMemsetAsync(d_ws, 0, (size_t)2 * BB * DD * DD * sizeof(float), stream);
  k_gram <<<dim3(8, BB),        512, 0, stream>>>(x, Gf);
  k_heads<<<dim3(2 * HH, BB),   512, 0, stream>>>(Gf, Wkq, Wv, Mf);
  k_out  <<<dim3(SS / 256, BB), 512, 0, stream>>>(x, Mf, out);
}